// Round 17
// baseline (48275.043 us; speedup 1.0000x reference)
//
#include <hip/hip_runtime.h>
#include <stdint.h>

#define B_SZ 64
#define T_SZ 2048
#define H_SZ 256
#define TH   (T_SZ * H_SZ)

typedef __attribute__((ext_vector_type(8))) short bf16x8_t;
typedef __attribute__((ext_vector_type(4))) float f32x4_t;

#if defined(__has_builtin)
#if __has_builtin(__builtin_amdgcn_sdot4)
#define HAVE_SDOT4 1
#endif
#endif
#ifndef HAVE_SDOT4
#define HAVE_SDOT4 0
#endif

static __device__ __forceinline__ int sdot4_(unsigned a, unsigned b, int acc){
#if HAVE_SDOT4
  return __builtin_amdgcn_sdot4((int)a, (int)b, acc, false);
#else
  #pragma unroll
  for(int i = 0; i < 4; ++i){
    int ai = (int)(a << (24 - 8*i)) >> 24;
    int bi = (int)(b << (24 - 8*i)) >> 24;
    acc += ai * bi;
  }
  return acc;
#endif
}

static __device__ __forceinline__ unsigned short f2bf(float f){
  unsigned int u = __float_as_uint(f);
  return (unsigned short)((u + 0x7fffu + ((u >> 16) & 1u)) >> 16);
}
static __device__ __forceinline__ unsigned short f2h(float f){
  return __builtin_bit_cast(unsigned short, (_Float16)f);
}
static __device__ __forceinline__ float h2f(unsigned short h){
  return (float)__builtin_bit_cast(_Float16, h);
}
static __device__ __forceinline__ float sigmoidf_(float x){
  return 1.f / (1.f + __expf(-x));
}
static __device__ __forceinline__ float tanhf_(float x){
  float e = __expf(-2.f * fabsf(x));
  float t = (1.f - e) / (1.f + e);
  return copysignf(t, x);
}
// Un-sinkable, un-rematerializable 16B load (volatile asm black box).
static __device__ __forceinline__ uint4 load16_opaque(const void* p){
  uint4 v;
  asm volatile("global_load_dwordx4 %0, %1, off"
               : "=v"(v) : "v"(p) : "memory");
  return v;
}

// ---------- pack recurrent weights to i8 with per-row scale ----------
// WP8[(g*16+c)*256 + j] : uint4 = 16 i8 k-values [16c,16c+16) of row j, gate g
__global__ __launch_bounds__(256) void prep_pack_i8(const float* __restrict__ Whr,
                                                    const float* __restrict__ Whz,
                                                    const float* __restrict__ WhN,
                                                    uint4* __restrict__ WP8,
                                                    float* __restrict__ scales){
  const int g = blockIdx.x;
  const int j = threadIdx.x;
  const float* W = (g == 0) ? Whr : ((g == 1) ? Whz : WhN);
  const float* row = W + j*256;
  float mx = 0.f;
  for(int k = 0; k < 256; k += 4){
    float4 v = *(const float4*)&row[k];
    mx = fmaxf(mx, fmaxf(fmaxf(fabsf(v.x), fabsf(v.y)), fmaxf(fabsf(v.z), fabsf(v.w))));
  }
  const float inv = (mx > 0.f) ? 127.f/mx : 0.f;
  scales[g*256 + j] = (mx > 0.f) ? mx/127.f : 0.f;
  for(int c = 0; c < 16; ++c){
    uint4 o; unsigned* op = (unsigned*)&o;
    #pragma unroll
    for(int m = 0; m < 4; ++m){
      float4 v = *(const float4*)&row[c*16 + m*4];
      unsigned b0 = (unsigned)((int)lrintf(v.x*inv) & 255);
      unsigned b1 = (unsigned)((int)lrintf(v.y*inv) & 255);
      unsigned b2 = (unsigned)((int)lrintf(v.z*inv) & 255);
      unsigned b3 = (unsigned)((int)lrintf(v.w*inv) & 255);
      op[m] = b0 | (b1 << 8) | (b2 << 16) | (b3 << 24);
    }
    WP8[(g*16 + c)*256 + j] = o;
  }
}

// ---------- zero the sync flags (runs before every scan launch) ----------
__global__ __launch_bounds__(256) void zero_flags(unsigned int* flags){
  int i = blockIdx.x*256 + threadIdx.x;
  if(i < 2048) flags[i] = 0u;
}

// ---------- X fp32 -> bf16 (dst aliases the xz slot of ws) ----------
__global__ __launch_bounds__(256) void cast_x(const float* __restrict__ X,
                                              unsigned short* __restrict__ XB){
  size_t i = ((size_t)blockIdx.x*256 + threadIdx.x)*8;
  float4 v0 = *(const float4*)&X[i];
  float4 v1 = *(const float4*)&X[i+4];
  ushort4 o0; o0.x=f2bf(v0.x); o0.y=f2bf(v0.y); o0.z=f2bf(v0.z); o0.w=f2bf(v0.w);
  ushort4 o1; o1.x=f2bf(v1.x); o1.y=f2bf(v1.y); o1.z=f2bf(v1.z); o1.w=f2bf(v1.w);
  *(ushort4*)&XB[i]   = o0;
  *(ushort4*)&XB[i+4] = o1;
}

// ---------- Wi{r,z,N} fp32 -> bf16, layout [g][n][k] ----------
__global__ __launch_bounds__(256) void cast_w(const float* __restrict__ Wir,
                                              const float* __restrict__ Wiz,
                                              const float* __restrict__ WiN,
                                              unsigned short* __restrict__ WB){
  size_t i = ((size_t)blockIdx.x*256 + threadIdx.x)*8;
  int g = (int)(i >> 16);
  int rem = (int)(i & 65535);
  const float* W = (g==0) ? Wir : ((g==1) ? Wiz : WiN);
  float4 v0 = *(const float4*)&W[rem];
  float4 v1 = *(const float4*)&W[rem+4];
  ushort4 o0; o0.x=f2bf(v0.x); o0.y=f2bf(v0.y); o0.z=f2bf(v0.z); o0.w=f2bf(v0.w);
  ushort4 o1; o1.x=f2bf(v1.x); o1.y=f2bf(v1.y); o1.z=f2bf(v1.z); o1.w=f2bf(v1.w);
  *(ushort4*)&WB[i]   = o0;
  *(ushort4*)&WB[i+4] = o1;
}

// ---------- input projection: [131072,256] @ WB[g]^T, bf16 MFMA ----------
__global__ __launch_bounds__(256) void proj_kernel(const unsigned short* __restrict__ XB,
                                                   const unsigned short* __restrict__ WB,
                                                   const float* __restrict__ bias,
                                                   const float* __restrict__ bias2,
                                                   unsigned short* __restrict__ dst16,
                                                   float* __restrict__ dst32){
  __shared__ unsigned short As[64][88];
  __shared__ unsigned short Bs[256][88];
  const int tid = threadIdx.x;
  const int m0 = blockIdx.x * 64;
  const int w  = tid >> 6;
  const int l  = tid & 63;
  const int l15 = l & 15;
  const int lq  = l >> 4;

  f32x4_t acc[16];
  #pragma unroll
  for(int i = 0; i < 16; ++i) acc[i] = (f32x4_t){0.f,0.f,0.f,0.f};

  for(int kc = 0; kc < 256; kc += 64){
    #pragma unroll
    for(int p = 0; p < 2; ++p){
      int e = (p*256 + tid)*8;
      int r = e >> 6, k = e & 63;
      *(uint4*)&As[r][k] = *(const uint4*)&XB[(size_t)(m0 + r)*256 + kc + k];
    }
    #pragma unroll
    for(int p = 0; p < 8; ++p){
      int e = (p*256 + tid)*8;
      int n = e >> 6, k = e & 63;
      *(uint4*)&Bs[n][k] = *(const uint4*)&WB[n*256 + kc + k];
    }
    __syncthreads();
    #pragma unroll
    for(int ks = 0; ks < 2; ++ks){
      bf16x8_t a = *(const bf16x8_t*)&As[w*16 + l15][ks*32 + lq*8];
      #pragma unroll
      for(int fc = 0; fc < 16; ++fc){
        bf16x8_t bfr = *(const bf16x8_t*)&Bs[fc*16 + l15][ks*32 + lq*8];
        acc[fc] = __builtin_amdgcn_mfma_f32_16x16x32_bf16(a, bfr, acc[fc], 0, 0, 0);
      }
    }
    __syncthreads();
  }
  #pragma unroll
  for(int fc = 0; fc < 16; ++fc){
    int col = fc*16 + l15;
    float bv = bias[col] + (bias2 ? bias2[col] : 0.f);
    #pragma unroll
    for(int ri = 0; ri < 4; ++ri){
      int row = w*16 + lq*4 + ri;
      size_t idx = (size_t)(m0 + row)*256 + col;
      float v = acc[fc][ri] + bv;
      if(dst32) dst32[idx] = v;
      else      dst16[idx] = f2h(v);
    }
  }
}

// ---------- recurrence: 4-way j-split, 256 blocks (all CUs), i8 dots -------
// R16's first-call failure was an ALLOCATION OVERLAP (flags placed 8 KB into
// the 32 KB hbuf -> batches 32-63 exchanged through stomped memory), not the
// protocol. R17: identical kernel, correct offsets (flags = hbuf + 32 KB).
// Exchange protocol (R12's race fixed): per-lane release/acquire pairing —
// each publishing lane stores its own 8B data element (relaxed) then ITS OWN
// flag (release); each fetching lane acquires exactly the flag guarding the
// element it reads. 2-deep hbuf rotation is safe via the happens-before chain.
__global__ __launch_bounds__(768) void scan_kernel(
    const uint4* __restrict__ WP8,
    const float* __restrict__ scales,
    const unsigned short* __restrict__ xr_g,
    const unsigned short* __restrict__ xz_g,
    float* out, float* __restrict__ hlast,
    const float* __restrict__ bhN,
    unsigned long long* hbuf, unsigned int* flags){
  __shared__ __align__(16) char hs8[2][4][64];   // h i8: [buf][slice][64]
  __shared__ float pr[64], pz[64];

  const int tid = threadIdx.x;
  const int o   = tid >> 2;       // 0..191
  const int ks  = tid & 3;        // k-quarter
  const int g   = o >> 6;         // gate
  const int jj  = o & 63;         // local j
  const int w   = tid >> 6;       // wave 0..11
  const int l   = tid & 63;
  const int bid = blockIdx.x;
  const int s   = bid >> 6;       // j-slice
  const int b   = bid & 63;       // batch
  const int j   = s*64 + jj;

  // weights: 4 uint4 opaque loads (completion: pre-loop barrier drains vmcnt)
  uint4 wreg[4];
  #pragma unroll
  for(int c = 0; c < 4; ++c)
    wreg[c] = load16_opaque((const char*)WP8 + (((size_t)(g*16 + ks*4 + c))*256 + j)*16);

  if(tid < 128) ((unsigned*)hs8)[tid] = 0u;      // h(0)=0, both buffers

  const float wscale = scales[g*256 + j] * (1.f/127.f);
  const float bn = (g == 2) ? bhN[j] : 0.f;
  float hp = 0.f;

  const char* px = nullptr; int stx = 0;
  if(ks == 0){
    if(g == 0){      px = (const char*)(xr_g + (size_t)b*TH + j); stx = 512;  }
    else if(g == 1){ px = (const char*)(xz_g + (size_t)b*TH + j); stx = 512;  }
    else{            px = (const char*)(out  + (size_t)b*TH + j); stx = 1024; } // xn fp32 in d_out
  }
  float xcur = 0.f;
  if(ks == 0) xcur = (g < 2) ? h2f(*(const unsigned short*)px) : *(const float*)px;

  float* pout = out + (size_t)b*TH + j;
  __syncthreads();   // drains vmcnt: weight loads complete; hs8 zeroed

  for(int t = 0; t < T_SZ; ++t){
    const int cur = t & 1, nxt = cur ^ 1;
    // prefetch x(t+1)
    float xnxt = 0.f;
    if(ks == 0 && t + 1 < T_SZ)
      xnxt = (g < 2) ? h2f(*(const unsigned short*)(px + stx)) : *(const float*)(px + stx);

    // ---- i8 dot over this thread's 64-k slice (slice ks of h) ----
    int a0 = 0, a1 = 0, a2 = 0, a3 = 0;
    #pragma unroll
    for(int c = 0; c < 4; ++c){
      uint4 hq = *(const uint4*)&hs8[cur][ks][c*16];
      a0 = sdot4_(wreg[c].x, hq.x, a0);
      a1 = sdot4_(wreg[c].y, hq.y, a1);
      a2 = sdot4_(wreg[c].z, hq.z, a2);
      a3 = sdot4_(wreg[c].w, hq.w, a3);
    }
    float sdot = (float)((a0 + a1) + (a2 + a3));
    sdot += __shfl_xor(sdot, 1, 64);
    sdot += __shfl_xor(sdot, 2, 64);   // all 4 ks lanes hold the full dot
    sdot *= wscale;

    if(ks == 0){
      if(g == 0)      pr[jj] = sigmoidf_(sdot + xcur);
      else if(g == 1) pz[jj] = sigmoidf_(sdot + xcur);
    }
    __syncthreads();   // A: pr/pz visible; hs8[cur] reads done

    if(g == 2){
      if(ks == 0){
        float n = tanhf_(xcur + pr[jj]*(sdot + bn));
        float z = pz[jj];
        float h = n + z*(hp - n);
        hp = h;
        pout[(size_t)t*256] = h;
        if(t + 1 < T_SZ) hs8[nxt][s][jj] = (char)(int)lrintf(h * 127.f);
        else             hlast[b*256 + j] = hp;
      }
      if(t + 1 < T_SZ){
        asm volatile("s_waitcnt lgkmcnt(0)" ::: "memory");   // own-wave LDS h writes done
        const int wq = w - 8;                                // 0..3: this wave's jj block
        if(l < 2){
          const int e = wq*2 + l;                            // element 0..7 (8B each)
          unsigned long long v = *(const unsigned long long*)&hs8[nxt][s][e*8];
          __hip_atomic_store(&hbuf[(((size_t)nxt*64 + b)*4 + s)*8 + e], v,
                             __ATOMIC_RELAXED, __HIP_MEMORY_SCOPE_AGENT);
          // SAME lane releases the flag guarding ITS element -> correct pairing
          __hip_atomic_store(&flags[(b*4 + s)*8 + e], (unsigned)(t + 1),
                             __ATOMIC_RELEASE, __HIP_MEMORY_SCOPE_AGENT);
        }
      }
    }else if(w >= 4 && w < 7 && t + 1 < T_SZ){
      // waves 4,5,6 fetch sibling slices s+1,s+2,s+3 (mod 4)
      const int sib = (s + 1 + (w - 4)) & 3;
      if(l < 8){
        const unsigned want = (unsigned)(t + 1);
        while(__hip_atomic_load(&flags[(b*4 + sib)*8 + l], __ATOMIC_ACQUIRE,
                                __HIP_MEMORY_SCOPE_AGENT) < want) {}
        unsigned long long v =
          __hip_atomic_load(&hbuf[(((size_t)nxt*64 + b)*4 + sib)*8 + l],
                            __ATOMIC_RELAXED, __HIP_MEMORY_SCOPE_AGENT);
        *(unsigned long long*)&hs8[nxt][sib][l*8] = v;
      }
    }
    __syncthreads();   // B: hs8[nxt] complete (own slice + 3 fetched)
    xcur = xnxt;
    if(ks == 0) px += stx;
  }
}

extern "C" void kernel_launch(void* const* d_in, const int* in_sizes, int n_in,
                              void* d_out, int out_size, void* d_ws, size_t ws_size,
                              hipStream_t stream){
  const float* X   = (const float*)d_in[0];
  const float* Wir = (const float*)d_in[1];
  const float* bir = (const float*)d_in[2];
  const float* Whr = (const float*)d_in[3];
  const float* bhr = (const float*)d_in[4];
  const float* Wiz = (const float*)d_in[5];
  const float* biz = (const float*)d_in[6];
  const float* Whz = (const float*)d_in[7];
  const float* bhz = (const float*)d_in[8];
  const float* WiN = (const float*)d_in[9];
  const float* biN = (const float*)d_in[10];
  const float* WhN = (const float*)d_in[11];
  const float* bhN = (const float*)d_in[12];

  float* out   = (float*)d_out;
  float* hlast = out + (size_t)B_SZ*TH;

  unsigned char* ws = (unsigned char*)d_ws;
  const size_t XN = (size_t)B_SZ*TH;                  // 33,554,432
  unsigned short* xr = (unsigned short*)ws;           // 67.1 MB f16
  unsigned short* xz = (unsigned short*)(ws + XN*2);  // 67.1 MB (bf16 X first, xz after)
  unsigned short* WB = (unsigned short*)(ws + XN*4);  // 384 KB bf16 input weights
  uint4* WP8    = (uint4*)(ws + XN*4 + 393216);       // 192 KB i8 recurrent weights
  float* scales = (float*)(ws + XN*4 + 393216 + 196608);                  // 3 KB
  // hbuf: 2 bufs x 64 batches x 4 slices x 8 elems x 8 B = 32768 B (R16 bug:
  // flags was at +8192, overlapping hbuf entries 1024..2047). flags AFTER it.
  unsigned long long* hbuf = (unsigned long long*)(ws + XN*4 + 655360);    // 32 KB
  unsigned int* flags      = (unsigned int*)(ws + XN*4 + 655360 + 32768);  // 8 KB
  unsigned short* XB = xz;                            // bf16 X aliases the xz slot

  cast_w<<<96, 256, 0, stream>>>(Wir, Wiz, WiN, WB);
  prep_pack_i8<<<3, 256, 0, stream>>>(Whr, Whz, WhN, WP8, scales);
  cast_x<<<16384, 256, 0, stream>>>(X, XB);
  // r-gate: fold bhr; n-gate: fp32 xn -> d_out (bhN applied in scan)
  proj_kernel<<<2048, 256, 0, stream>>>(XB, WB,           bir, bhr,     xr, nullptr);
  proj_kernel<<<2048, 256, 0, stream>>>(XB, WB + 2*65536, biN, nullptr, nullptr, out);
  // z LAST: writes xz in place over XB (block reads whole A-tile before epilogue)
  proj_kernel<<<2048, 256, 0, stream>>>(XB, WB + 65536,   biz, bhz,     xz, nullptr);
  zero_flags<<<8, 256, 0, stream>>>(flags);
  scan_kernel<<<256, 768, 0, stream>>>(WP8, scales, xr, xz, out, hlast, bhN, hbuf, flags);
}

// Round 18
// 2238.055 us; speedup vs baseline: 21.5701x; 21.5701x over previous
//
#include <hip/hip_runtime.h>
#include <stdint.h>

#define B_SZ 64
#define T_SZ 2048
#define H_SZ 256
#define TH   (T_SZ * H_SZ)
#define CRES 6             // weight chunks resident in LDS
#define NREG 10            // weight chunks resident in registers (40 VGPRs, opaque loads)

typedef __attribute__((ext_vector_type(8))) short bf16x8_t;
typedef __attribute__((ext_vector_type(4))) float f32x4_t;

#if defined(__has_builtin)
#if __has_builtin(__builtin_amdgcn_sdot4)
#define HAVE_SDOT4 1
#endif
#endif
#ifndef HAVE_SDOT4
#define HAVE_SDOT4 0
#endif

static __device__ __forceinline__ int sdot4_(unsigned a, unsigned b, int acc){
#if HAVE_SDOT4
  return __builtin_amdgcn_sdot4((int)a, (int)b, acc, false);
#else
  #pragma unroll
  for(int i = 0; i < 4; ++i){
    int ai = (int)(a << (24 - 8*i)) >> 24;
    int bi = (int)(b << (24 - 8*i)) >> 24;
    acc += ai * bi;
  }
  return acc;
#endif
}

static __device__ __forceinline__ unsigned short f2bf(float f){
  unsigned int u = __float_as_uint(f);
  return (unsigned short)((u + 0x7fffu + ((u >> 16) & 1u)) >> 16);
}
static __device__ __forceinline__ unsigned short f2h(float f){
  return __builtin_bit_cast(unsigned short, (_Float16)f);
}
static __device__ __forceinline__ float sigmoidf_(float x){
  return 1.f / (1.f + __expf(-x));
}
static __device__ __forceinline__ float tanhf_(float x){
  float e = __expf(-2.f * fabsf(x));
  float t = (1.f - e) / (1.f + e);
  return copysignf(t, x);
}
// global -> LDS async DMA: per-lane global src, LDS dest = uniform base + lane*16
static __device__ __forceinline__ void stage16(const void* g, void* l){
  __builtin_amdgcn_global_load_lds(
      (const __attribute__((address_space(1))) unsigned int*)g,
      (__attribute__((address_space(3))) unsigned int*)l, 16, 0, 0);
}
// Un-sinkable, un-rematerializable 16B load (volatile asm black box).
// Completion guaranteed by the next __syncthreads() (drains vmcnt).
static __device__ __forceinline__ uint4 load16_opaque(const void* p){
  uint4 v;
  asm volatile("global_load_dwordx4 %0, %1, off"
               : "=v"(v) : "v"(p) : "memory");
  return v;
}

// ---------- pack recurrent weights to i8 with per-row scale ----------
// WP8[(g*16+c)*256 + j] : uint4 = 16 i8 k-values [16c,16c+16) of row j, gate g
__global__ __launch_bounds__(256) void prep_pack_i8(const float* __restrict__ Whr,
                                                    const float* __restrict__ Whz,
                                                    const float* __restrict__ WhN,
                                                    uint4* __restrict__ WP8,
                                                    float* __restrict__ scales){
  const int g = blockIdx.x;
  const int j = threadIdx.x;
  const float* W = (g == 0) ? Whr : ((g == 1) ? Whz : WhN);
  const float* row = W + j*256;
  float mx = 0.f;
  for(int k = 0; k < 256; k += 4){
    float4 v = *(const float4*)&row[k];
    mx = fmaxf(mx, fmaxf(fmaxf(fabsf(v.x), fabsf(v.y)), fmaxf(fabsf(v.z), fabsf(v.w))));
  }
  const float inv = (mx > 0.f) ? 127.f/mx : 0.f;
  scales[g*256 + j] = (mx > 0.f) ? mx/127.f : 0.f;
  for(int c = 0; c < 16; ++c){
    uint4 o; unsigned* op = (unsigned*)&o;
    #pragma unroll
    for(int m = 0; m < 4; ++m){
      float4 v = *(const float4*)&row[c*16 + m*4];
      unsigned b0 = (unsigned)((int)lrintf(v.x*inv) & 255);
      unsigned b1 = (unsigned)((int)lrintf(v.y*inv) & 255);
      unsigned b2 = (unsigned)((int)lrintf(v.z*inv) & 255);
      unsigned b3 = (unsigned)((int)lrintf(v.w*inv) & 255);
      op[m] = b0 | (b1 << 8) | (b2 << 16) | (b3 << 24);
    }
    WP8[(g*16 + c)*256 + j] = o;
  }
}

// ---------- X fp32 -> bf16 (dst aliases the xz slot of ws) ----------
__global__ __launch_bounds__(256) void cast_x(const float* __restrict__ X,
                                              unsigned short* __restrict__ XB){
  size_t i = ((size_t)blockIdx.x*256 + threadIdx.x)*8;
  float4 v0 = *(const float4*)&X[i];
  float4 v1 = *(const float4*)&X[i+4];
  ushort4 o0; o0.x=f2bf(v0.x); o0.y=f2bf(v0.y); o0.z=f2bf(v0.z); o0.w=f2bf(v0.w);
  ushort4 o1; o1.x=f2bf(v1.x); o1.y=f2bf(v1.y); o1.z=f2bf(v1.z); o1.w=f2bf(v1.w);
  *(ushort4*)&XB[i]   = o0;
  *(ushort4*)&XB[i+4] = o1;
}

// ---------- Wi{r,z,N} fp32 -> bf16, layout [g][n][k] ----------
__global__ __launch_bounds__(256) void cast_w(const float* __restrict__ Wir,
                                              const float* __restrict__ Wiz,
                                              const float* __restrict__ WiN,
                                              unsigned short* __restrict__ WB){
  size_t i = ((size_t)blockIdx.x*256 + threadIdx.x)*8;
  int g = (int)(i >> 16);
  int rem = (int)(i & 65535);
  const float* W = (g==0) ? Wir : ((g==1) ? Wiz : WiN);
  float4 v0 = *(const float4*)&W[rem];
  float4 v1 = *(const float4*)&W[rem+4];
  ushort4 o0; o0.x=f2bf(v0.x); o0.y=f2bf(v0.y); o0.z=f2bf(v0.z); o0.w=f2bf(v0.w);
  ushort4 o1; o1.x=f2bf(v1.x); o1.y=f2bf(v1.y); o1.z=f2bf(v1.z); o1.w=f2bf(v1.w);
  *(ushort4*)&WB[i]   = o0;
  *(ushort4*)&WB[i+4] = o1;
}

// ---------- input projection: [131072,256] @ WB[g]^T, bf16 MFMA ----------
__global__ __launch_bounds__(256) void proj_kernel(const unsigned short* __restrict__ XB,
                                                   const unsigned short* __restrict__ WB,
                                                   const float* __restrict__ bias,
                                                   const float* __restrict__ bias2,
                                                   unsigned short* __restrict__ dst16,
                                                   float* __restrict__ dst32){
  __shared__ unsigned short As[64][88];
  __shared__ unsigned short Bs[256][88];
  const int tid = threadIdx.x;
  const int m0 = blockIdx.x * 64;
  const int w  = tid >> 6;
  const int l  = tid & 63;
  const int l15 = l & 15;
  const int lq  = l >> 4;

  f32x4_t acc[16];
  #pragma unroll
  for(int i = 0; i < 16; ++i) acc[i] = (f32x4_t){0.f,0.f,0.f,0.f};

  for(int kc = 0; kc < 256; kc += 64){
    #pragma unroll
    for(int p = 0; p < 2; ++p){
      int e = (p*256 + tid)*8;
      int r = e >> 6, k = e & 63;
      *(uint4*)&As[r][k] = *(const uint4*)&XB[(size_t)(m0 + r)*256 + kc + k];
    }
    #pragma unroll
    for(int p = 0; p < 8; ++p){
      int e = (p*256 + tid)*8;
      int n = e >> 6, k = e & 63;
      *(uint4*)&Bs[n][k] = *(const uint4*)&WB[n*256 + kc + k];
    }
    __syncthreads();
    #pragma unroll
    for(int ks = 0; ks < 2; ++ks){
      bf16x8_t a = *(const bf16x8_t*)&As[w*16 + l15][ks*32 + lq*8];
      #pragma unroll
      for(int fc = 0; fc < 16; ++fc){
        bf16x8_t bfr = *(const bf16x8_t*)&Bs[fc*16 + l15][ks*32 + lq*8];
        acc[fc] = __builtin_amdgcn_mfma_f32_16x16x32_bf16(a, bfr, acc[fc], 0, 0, 0);
      }
    }
    __syncthreads();
  }
  #pragma unroll
  for(int fc = 0; fc < 16; ++fc){
    int col = fc*16 + l15;
    float bv = bias[col] + (bias2 ? bias2[col] : 0.f);
    #pragma unroll
    for(int ri = 0; ri < 4; ++ri){
      int row = w*16 + lq*4 + ri;
      size_t idx = (size_t)(m0 + row)*256 + col;
      float v = acc[fc][ri] + bv;
      if(dst32) dst32[idx] = v;
      else      dst16[idx] = f2h(v);
    }
  }
}

// ---------- recurrence: i8-dot scan, 1 block per batch, 64 blocks ----------
// R15 (2145us scan) is LDS-pipe bound: 120 per-lane weight ds_read_b128/step
// (~1440 cy) + 192 uniform h broadcasts (~770 cy). R17's cross-block split is
// dead (atomic exchange ~23us/step). R18: single-variable change from R15 —
// NREG 6->10, CRES 10->6: 40 weight VGPRs (demand ~84 = the allocator ceiling
// observed in R9/R10/R11), weight LDS reads drop 10->6 per thread.
__global__ __launch_bounds__(768) void scan_kernel(
    const uint4* __restrict__ WP8,
    const float* __restrict__ scales,
    const unsigned short* __restrict__ xr_g,
    const unsigned short* __restrict__ xz_g,
    float* __restrict__ out, float* __restrict__ hlast,
    const float* __restrict__ bhN){
  __shared__ uint4 WL[3][CRES][256];                // 72 KB i8 weights, chunks 0..CRES-1
  __shared__ __align__(16) char hs8[256];           // h as i8 (single buffer, 2 barriers/step)
  __shared__ __align__(16) _Float16 xr_sh[2][512];  // 2 steps per buffer
  __shared__ __align__(16) _Float16 xz_sh[2][512];
  __shared__ __align__(16) float    xn_sh[2][512];
  __shared__ float pr[256], pz[256];

  const int tid = threadIdx.x;
  const int g = tid >> 8;        // gate
  const int j = tid & 255;       // output row
  const int w = tid >> 6;        // wave 0..11
  const int l = tid & 63;
  const int b = blockIdx.x;

  // register-resident chunks CRES..15 (opaque loads -> cannot sink/remat)
  uint4 wreg[NREG];
  #pragma unroll
  for(int c = 0; c < NREG; ++c)
    wreg[c] = load16_opaque((const char*)WP8 + (((size_t)(g*16 + CRES + c))*256 + j)*16);

  // fill LDS weight chunks 0..CRES-1 (one-time, 72 KB from L2)
  for(int i = tid; i < 3*CRES*256; i += 768){
    int gg = i / (CRES*256);
    int rem = i - gg*(CRES*256);
    int cc = rem >> 8, jj = rem & 255;
    WL[gg][cc][jj] = WP8[(gg*16 + cc)*256 + jj];
  }
  if(tid < 64) ((unsigned*)hs8)[tid] = 0u;          // h(0) = 0

  const float wscale = scales[g*256 + j] * (1.f/127.f);
  const float bn = (g == 2) ? bhN[j] : 0.f;
  float hp = 0.f;

  const char* xr_b = (const char*)(xr_g + (size_t)b*TH);
  const char* xz_b = (const char*)(xz_g + (size_t)b*TH);
  const char* xn_b = (const char*)(out + (size_t)b*TH);       // xn fp32 lives in d_out
  float* out_b = out + (size_t)b*TH;

  // stage steps 0,1 into buffer 0 (1 KB per DMA wave)
  if(w == 0)      stage16(xr_b + l*16, &xr_sh[0][0]);
  else if(w == 1) stage16(xz_b + l*16, &xz_sh[0][0]);
  else if(w == 2) stage16(xn_b + l*16, &xn_sh[0][0]);
  else if(w == 3) stage16(xn_b + 1024 + l*16, &xn_sh[0][256]);
  __syncthreads();   // drains vmcnt: opaque weight loads + LDS fill + staging

  for(int t = 0; t < T_SZ; ++t){
    const int pb = (t >> 1) & 1;
    if((t & 1) == 0 && t + 2 < T_SZ){
      const int nb = pb ^ 1;
      if(w == 0)      stage16(xr_b + (t+2)*512  + l*16, &xr_sh[nb][0]);
      else if(w == 1) stage16(xz_b + (t+2)*512  + l*16, &xz_sh[nb][0]);
      else if(w == 2) stage16(xn_b + (t+2)*1024 + l*16, &xn_sh[nb][0]);
      else if(w == 3) stage16(xn_b + (t+2)*1024 + 1024 + l*16, &xn_sh[nb][256]);
    }

    // ---- 256-wide i8 dot: exact integer accumulation, 4 chains ----
    int a0 = 0, a1 = 0, a2 = 0, a3 = 0;
    #pragma unroll
    for(int c = 0; c < CRES; ++c){
      uint4 wq = WL[g][c][j];
      uint4 hq = *(const uint4*)(hs8 + c*16);       // wave-uniform broadcast
      a0 = sdot4_(wq.x, hq.x, a0);
      a1 = sdot4_(wq.y, hq.y, a1);
      a2 = sdot4_(wq.z, hq.z, a2);
      a3 = sdot4_(wq.w, hq.w, a3);
    }
    #pragma unroll
    for(int c = 0; c < NREG; ++c){
      uint4 hq = *(const uint4*)(hs8 + (CRES + c)*16);
      a0 = sdot4_(wreg[c].x, hq.x, a0);
      a1 = sdot4_(wreg[c].y, hq.y, a1);
      a2 = sdot4_(wreg[c].z, hq.z, a2);
      a3 = sdot4_(wreg[c].w, hq.w, a3);
    }
    const float s = (float)((a0 + a1) + (a2 + a3)) * wscale;

    const int to = (t & 1) << 8;
    if(g == 0)      pr[j] = sigmoidf_(s + (float)xr_sh[pb][to + j]);
    else if(g == 1) pz[j] = sigmoidf_(s + (float)xz_sh[pb][to + j]);
    __syncthreads();   // A: pr/pz visible; all hs8 reads of step t done

    if(g == 2){
      float xn = xn_sh[pb][to + j];
      float n  = tanhf_(xn + pr[j]*(s + bn));
      float z  = pz[j];
      float hn = n + z*(hp - n);
      hp = hn;
      out_b[t*256 + j] = hn;
      hs8[j] = (char)(int)lrintf(hn * 127.f);   // h for step t+1 (i8)
    }
    __syncthreads();   // B: h visible before next step's dots
  }
  if(g == 2) hlast[b*256 + j] = hp;
}

extern "C" void kernel_launch(void* const* d_in, const int* in_sizes, int n_in,
                              void* d_out, int out_size, void* d_ws, size_t ws_size,
                              hipStream_t stream){
  const float* X   = (const float*)d_in[0];
  const float* Wir = (const float*)d_in[1];
  const float* bir = (const float*)d_in[2];
  const float* Whr = (const float*)d_in[3];
  const float* bhr = (const float*)d_in[4];
  const float* Wiz = (const float*)d_in[5];
  const float* biz = (const float*)d_in[6];
  const float* Whz = (const float*)d_in[7];
  const float* bhz = (const float*)d_in[8];
  const float* WiN = (const float*)d_in[9];
  const float* biN = (const float*)d_in[10];
  const float* WhN = (const float*)d_in[11];
  const float* bhN = (const float*)d_in[12];

  float* out   = (float*)d_out;
  float* hlast = out + (size_t)B_SZ*TH;

  unsigned char* ws = (unsigned char*)d_ws;
  const size_t XN = (size_t)B_SZ*TH;                  // 33,554,432
  unsigned short* xr = (unsigned short*)ws;           // 67.1 MB f16
  unsigned short* xz = (unsigned short*)(ws + XN*2);  // 67.1 MB (bf16 X first, xz after)
  unsigned short* WB = (unsigned short*)(ws + XN*4);  // 384 KB bf16 input weights
  uint4* WP8   = (uint4*)(ws + XN*4 + 393216);        // 192 KB i8 recurrent weights
  float* scales = (float*)(ws + XN*4 + 393216 + 196608); // 3 KB row scales
  unsigned short* XB = xz;                            // bf16 X aliases the xz slot

  cast_w<<<96, 256, 0, stream>>>(Wir, Wiz, WiN, WB);
  prep_pack_i8<<<3, 256, 0, stream>>>(Whr, Whz, WhN, WP8, scales);
  cast_x<<<16384, 256, 0, stream>>>(X, XB);
  // r-gate: fold bhr; n-gate: fp32 xn -> d_out (bhN applied in scan)
  proj_kernel<<<2048, 256, 0, stream>>>(XB, WB,           bir, bhr,     xr, nullptr);
  proj_kernel<<<2048, 256, 0, stream>>>(XB, WB + 2*65536, biN, nullptr, nullptr, out);
  // z LAST: writes xz in place over XB (block reads whole A-tile before epilogue)
  proj_kernel<<<2048, 256, 0, stream>>>(XB, WB + 65536,   biz, bhz,     xz, nullptr);
  scan_kernel<<<64, 768, 0, stream>>>(WP8, scales, xr, xz, out, hlast, bhN);
}